// Round 14
// baseline (45.692 us; speedup 1.0000x reference)
//
#include <hip/hip_runtime.h>
#include <math.h>

#define CLS_NUM 1000
#define FEAT 512

// Champion 3-node structure (memset -> dist -> final), packed 8 B bins.
// R14 delta: software-prefetch the NEXT sample's label so the
// ys[i] -> center-addr -> center-load dependency chain hides under the
// current row's 4 KB of streaming loads.
// Structural ledger (totals): 3-node packed 45.0 | 3-node split 46.8 |
// count-first 57-60 | LDS-bins 60.8 | relaxed fused 57.1 | acq_rel fused
// 107 | fence fused 372 | cooperative: container deaths. Memset is
// irreducible (atomics need pre-zeroed bins; cross-call state forbidden).
// xs loads stay CACHEABLE on purpose: L3 retains ~40 MB across replays
// (FETCH 87 MB < 128 MB); nontemporal would forfeit that.

__global__ __launch_bounds__(256) void center_loss_dist(
    const float* __restrict__ xs,
    const void* __restrict__ ys_raw,
    const float* __restrict__ center,
    unsigned long long* __restrict__ bins,   // [CLS_NUM] {f32 ds, u32 cnt}
    int n)
{
    // Detect int64 vs int32 labels: for int64 (little-endian) the high
    // 32-bit word of each element is 0 and low word < 1000. For int32,
    // odd words are random labels; all-zero across 16 slots ~ 1e-48.
    const int* y32 = (const int*)ys_raw;
    bool is64 = true;
    #pragma unroll
    for (int k = 0; k < 16; ++k) {
        int lo = y32[2 * k], hi = y32[2 * k + 1];
        if (hi != 0 || (unsigned)lo >= (unsigned)CLS_NUM) is64 = false;
    }
    const long long* y64 = (const long long*)ys_raw;

    const int lane  = threadIdx.x & 63;
    const int wave  = (int)((blockIdx.x * blockDim.x + threadIdx.x) >> 6);
    const int nwave = (int)((gridDim.x * blockDim.x) >> 6);

    int i = wave;
    int y = (i < n) ? (is64 ? (int)y64[i] : y32[i]) : 0;

    while (i < n) {
        // Prefetch next label NOW so its latency (and the dependent
        // center-row address) hides under this row's streaming loads.
        const int inext = i + nwave;
        const int ynext = (inext < n) ? (is64 ? (int)y64[inext] : y32[inext]) : 0;

        const float4* xp = (const float4*)(xs + (size_t)i * FEAT);
        const float4* cp = (const float4*)(center + (size_t)y * FEAT);
        // Fully coalesced: lane l reads float4 #l and #(l+64) of the row.
        float4 x0 = xp[lane];
        float4 x1 = xp[lane + 64];
        float4 c0 = cp[lane];
        float4 c1 = cp[lane + 64];
        float d, s = 0.f;
        d = x0.x - c0.x; s += d * d;
        d = x0.y - c0.y; s += d * d;
        d = x0.z - c0.z; s += d * d;
        d = x0.w - c0.w; s += d * d;
        d = x1.x - c1.x; s += d * d;
        d = x1.y - c1.y; s += d * d;
        d = x1.z - c1.z; s += d * d;
        d = x1.w - c1.w; s += d * d;
        #pragma unroll
        for (int off = 32; off; off >>= 1)
            s += __shfl_xor(s, off, 64);
        if (lane == 0) {
            float* dsp    = (float*)&bins[y];
            unsigned* cp2 = (unsigned*)&bins[y] + 1;
            atomicAdd(dsp, sqrtf(s));
            atomicAdd(cp2, 1u);
        }

        i = inext;
        y = ynext;
    }
}

// out = sum_c ds_c / cnt_c  (cnt>0 guard; absent classes add 0)
__global__ __launch_bounds__(256) void center_loss_final(
    const unsigned long long* __restrict__ bins,
    float* __restrict__ out)
{
    float s = 0.f;
    for (int c = (int)threadIdx.x; c < CLS_NUM; c += 256) {
        unsigned long long p = bins[c];          // one 8 B load per class
        unsigned cnt = (unsigned)(p >> 32);
        float ds = __uint_as_float((unsigned)(p & 0xffffffffULL));
        if (cnt) s += ds / (float)cnt;
    }
    #pragma unroll
    for (int off = 32; off; off >>= 1)
        s += __shfl_xor(s, off, 64);
    __shared__ float wsum[4];
    if ((threadIdx.x & 63) == 0) wsum[threadIdx.x >> 6] = s;
    __syncthreads();
    if (threadIdx.x == 0)
        out[0] = wsum[0] + wsum[1] + wsum[2] + wsum[3];
}

extern "C" void kernel_launch(void* const* d_in, const int* in_sizes, int n_in,
                              void* d_out, int out_size, void* d_ws, size_t ws_size,
                              hipStream_t stream)
{
    const float* xs     = (const float*)d_in[0];
    const void*  ys     = d_in[1];
    const float* center = (const float*)d_in[2];
    float* out = (float*)d_out;

    // ws layout: bins[1000] = {f32 distsum, u32 count} pairs, 8000 bytes
    unsigned long long* bins = (unsigned long long*)d_ws;
    hipMemsetAsync(d_ws, 0, CLS_NUM * 8, stream);

    const int n = in_sizes[1];  // number of samples (ys element count)

    center_loss_dist<<<2048, 256, 0, stream>>>(xs, ys, center, bins, n);
    center_loss_final<<<1, 256, 0, stream>>>(bins, out);
}